// Round 6
// baseline (618.582 us; speedup 1.0000x reference)
//
#include <hip/hip_runtime.h>

typedef unsigned short u16;
typedef __attribute__((ext_vector_type(8))) short s16x8;
typedef __attribute__((ext_vector_type(4))) float f32x4;

__device__ __forceinline__ u16 f2bf(float f) {
  unsigned u = __float_as_uint(f);
  u += 0x7fffu + ((u >> 16) & 1u);   // RNE
  return (u16)(u >> 16);
}
__device__ __forceinline__ float bf2f(u16 h) {
  return __uint_as_float(((unsigned)h) << 16);
}

typedef __attribute__((address_space(1))) const void gvoid_t;
typedef __attribute__((address_space(3))) void lvoid_t;
__device__ __forceinline__ void gload_lds16(const void* g, void* l) {
  __builtin_amdgcn_global_load_lds((gvoid_t*)g, (lvoid_t*)l, 16, 0, 0);
}

// ---------------- f32 -> bf16 convert (vectorized) ----------------
__global__ void cvt_f32_bf16(const float* __restrict__ in, u16* __restrict__ out, int n) {
  int i = (blockIdx.x * 256 + threadIdx.x) * 4;
  if (i >= n) return;
  float4 v = *(const float4*)(in + i);
  ushort4 o;
  o.x = f2bf(v.x); o.y = f2bf(v.y); o.z = f2bf(v.z); o.w = f2bf(v.w);
  *(ushort4*)(out + i) = o;
}

// ---------------- GEMM v3: C[M,N] = A[M,K]*B[N,K]^T ----------------
// BM=128, BN=256, BK=64, 512 thr (8 waves 2Mx4N, per-wave 64x64).
// Triple-buffered LDS (144KB), 4-phase fine interleave per K-tile
// (m196/m201: the phase-split IS the prerequisite for T2/T4/T5 gains),
// counted vmcnt(6) once per K-tile, T2 XOR swizzle, T5 setprio.
template<typename OutT, bool BIAS>
__global__ __launch_bounds__(512) void gemm_bt2(
    const u16* __restrict__ A, const u16* __restrict__ Bm,
    OutT* __restrict__ C, const float* __restrict__ bias,
    int M, int N, int K)
{
  __shared__ u16 As[3][128 * 64];
  __shared__ u16 Bs[3][256 * 64];

  const int t = threadIdx.x;
  const int lane = t & 63, wid = t >> 6;
  const int wm = wid >> 2, wn = wid & 3;
  const int lr = lane & 15, lk = lane >> 4;

  // XCD swizzle: 256 blocks = 8 XCD x (16 m-blocks x 2 n-blocks)
  const int wg = blockIdx.x;
  const int xcd = wg & 7, j = wg >> 3;
  const int m0 = (j & 15) * 128;
  const int n0 = ((xcd << 1) | (j >> 4)) * 256;

  const int nt = K >> 6;

  f32x4 acc[4][4] = {};

  // A tile: rows 0..127 (2 x 512 thr); B tile: rows 0..255 (4 x 512 thr, split in halves)
#define STAGE_A(KT)                                                            \
  {                                                                            \
    const int bu_ = ((unsigned)(KT)) % 3u;                                     \
    const int k0_ = (KT) << 6;                                                 \
    _Pragma("unroll")                                                          \
    for (int it = 0; it < 2; ++it) {                                           \
      int id = it * 512 + t;                                                   \
      int r = id >> 3, c0 = id & 7;                                            \
      gload_lds16(A + (size_t)(m0 + r) * K + k0_ + ((c0 ^ (r & 7)) << 3),      \
                  &As[bu_][id * 8]);                                           \
    }                                                                          \
  }
#define STAGE_B(KT, HALF)                                                      \
  {                                                                            \
    const int bu_ = ((unsigned)(KT)) % 3u;                                     \
    const int k0_ = (KT) << 6;                                                 \
    _Pragma("unroll")                                                          \
    for (int it = 0; it < 2; ++it) {                                           \
      int id = ((HALF) * 2 + it) * 512 + t;                                    \
      int r = id >> 3, c0 = id & 7;                                            \
      gload_lds16(Bm + (size_t)(n0 + r) * K + k0_ + ((c0 ^ (r & 7)) << 3),     \
                  &Bs[bu_][id * 8]);                                           \
    }                                                                          \
  }

  // prologue: tiles 0,1 in flight (12 loads each wave); vmcnt(6) -> tile 0 landed
  STAGE_A(0); STAGE_B(0, 0); STAGE_B(0, 1);
  STAGE_A(1); STAGE_B(1, 0); STAGE_B(1, 1);
  asm volatile("s_waitcnt vmcnt(6)" ::: "memory");
  __builtin_amdgcn_s_barrier();

  for (int kt = 0; kt < nt; ++kt) {
    const int bu = ((unsigned)kt) % 3u;
    const bool st = (kt + 2 < nt);

#pragma unroll
    for (int ks = 0; ks < 2; ++ks) {
      // ---- phase (ks, ih=0): read bf[0..3] + af rows 0,1 ; stage A (ks0) / B-half1 (ks1)
      s16x8 bf[4];
#pragma unroll
      for (int jn = 0; jn < 4; ++jn) {
        int rb = wn * 64 + jn * 16 + lr;
        bf[jn] = *(const s16x8*)&Bs[bu][rb * 64 + (((ks * 4 + lk) ^ (rb & 7)) << 3)];
      }
      s16x8 af0[2];
#pragma unroll
      for (int ii = 0; ii < 2; ++ii) {
        int ra = wm * 64 + ii * 16 + lr;
        af0[ii] = *(const s16x8*)&As[bu][ra * 64 + (((ks * 4 + lk) ^ (ra & 7)) << 3)];
      }
      if (st) { if (ks == 0) STAGE_A(kt + 2) else STAGE_B(kt + 2, 1) }
      __builtin_amdgcn_s_barrier();
      asm volatile("s_waitcnt lgkmcnt(0)" ::: "memory");
      __builtin_amdgcn_sched_barrier(0);
      __builtin_amdgcn_s_setprio(1);
#pragma unroll
      for (int ii = 0; ii < 2; ++ii)
#pragma unroll
        for (int jn = 0; jn < 4; ++jn)
          acc[ii][jn] = __builtin_amdgcn_mfma_f32_16x16x32_bf16(af0[ii], bf[jn], acc[ii][jn], 0, 0, 0);
      __builtin_amdgcn_s_setprio(0);
      __builtin_amdgcn_s_barrier();

      // ---- phase (ks, ih=1): read af rows 2,3 (bf persists in regs); stage B-half0 (ks0)
      s16x8 af1[2];
#pragma unroll
      for (int ii = 0; ii < 2; ++ii) {
        int ra = wm * 64 + (2 + ii) * 16 + lr;
        af1[ii] = *(const s16x8*)&As[bu][ra * 64 + (((ks * 4 + lk) ^ (ra & 7)) << 3)];
      }
      if (st && ks == 0) STAGE_B(kt + 2, 0);
      if (ks == 1) {
        // rendezvous: each wave's outstanding <= 6 (= tile kt+2's); after the
        // following barrier, buf[(kt+1)%3] is collectively complete.
        if (st)                { asm volatile("s_waitcnt vmcnt(6)" ::: "memory"); }
        else if (kt + 2 == nt) { asm volatile("s_waitcnt vmcnt(0)" ::: "memory"); }
      }
      __builtin_amdgcn_s_barrier();
      asm volatile("s_waitcnt lgkmcnt(0)" ::: "memory");
      __builtin_amdgcn_sched_barrier(0);
      __builtin_amdgcn_s_setprio(1);
#pragma unroll
      for (int ii = 0; ii < 2; ++ii)
#pragma unroll
        for (int jn = 0; jn < 4; ++jn)
          acc[2 + ii][jn] = __builtin_amdgcn_mfma_f32_16x16x32_bf16(af1[ii], bf[jn], acc[2 + ii][jn], 0, 0, 0);
      __builtin_amdgcn_s_setprio(0);
      if (!(ks == 1 && kt == nt - 1)) __builtin_amdgcn_s_barrier();
    }
  }
#undef STAGE_A
#undef STAGE_B

  // epilogue: D layout col=lane&15 (B-row), row=(lane>>4)*4+reg (A-row)
#pragma unroll
  for (int i = 0; i < 4; ++i) {
    int row_b = m0 + wm * 64 + i * 16 + lk * 4;
#pragma unroll
    for (int jn = 0; jn < 4; ++jn) {
      int col = n0 + wn * 64 + jn * 16 + lr;
      float bv = BIAS ? bias[col] : 0.f;
#pragma unroll
      for (int r = 0; r < 4; ++r) {
        float v = acc[i][jn][r] + bv;
        size_t off = (size_t)(row_b + r) * N + col;
        if constexpr (sizeof(OutT) == 2) ((u16*)C)[off] = f2bf(v);
        else                             ((float*)C)[off] = v;
      }
    }
  }
}

// ---------------- RoPE on Q and K in place (bf16) ----------------
__global__ void rope_qk(u16* __restrict__ Q, u16* __restrict__ Kt,
                        const float* __restrict__ cosp, const float* __restrict__ sinp) {
  int i = blockIdx.x * 256 + threadIdx.x;   // over S*H*64
  int d = i & 63;
  int h = (i >> 6) & 31;
  int s = i >> 11;
  float c = cosp[s * 128 + d], sn = sinp[s * 128 + d];
  size_t base = (size_t)s * 4096 + h * 128 + d;
  float q1 = bf2f(Q[base]), q2 = bf2f(Q[base + 64]);
  Q[base]      = f2bf(q1 * c - q2 * sn);
  Q[base + 64] = f2bf(q2 * c + q1 * sn);
  float k1 = bf2f(Kt[base]), k2 = bf2f(Kt[base + 64]);
  Kt[base]      = f2bf(k1 * c - k2 * sn);
  Kt[base + 64] = f2bf(k2 * c + k1 * sn);
}

// ---------------- Flash attention (causal): QBLK=128, KVBLK=64, 8 waves ----------------
__global__ __launch_bounds__(512) void flash_attn(
    const u16* __restrict__ Q, const u16* __restrict__ Kg, const u16* __restrict__ Vg,
    u16* __restrict__ Ctx)
{
  const int D = 4096;
  __shared__ u16 Ks[2][64 * 128];  // [kv][d-chunk], chunk XOR-swizzled by (kv&7)
  __shared__ u16 Vt[2][128 * 64];  // [d][kv], kv XOR-swizzled by (((d>>3)^d)&7)<<3
  __shared__ u16 Ps[8][16 * 64];   // per-wave P, col XOR-swizzled by ((q>>1)&7)<<3

  const int t = threadIdx.x, lane = t & 63, wid = t >> 6;
  const int lr = lane & 15, lk = lane >> 4;

  const int wg = blockIdx.x;              // 0..511
  const int xcd = wg & 7, j = wg >> 3;    // j 0..63 local
  const int bx = 15 - (j >> 2);           // LPT: longest first
  const int h = xcd * 4 + (j & 3);        // 4 heads per XCD
  const int q0 = bx * 128;
  const int qw0 = q0 + wid * 16;

  s16x8 qf[4];
#pragma unroll
  for (int kc = 0; kc < 4; ++kc)
    qf[kc] = *(const s16x8*)(Q + (size_t)(qw0 + lr) * D + h * 128 + kc * 32 + lk * 8);

  f32x4 o[8] = {};
  float m_r[4] = {-1e30f, -1e30f, -1e30f, -1e30f};
  float l_r[4] = {0.f, 0.f, 0.f, 0.f};

  const int ntiles = 2 * bx + 2;
  const float scale2 = 0.12751779f;       // (1/sqrt(128)) * log2(e)

  const int ch = t & 15, kv2 = (t >> 4) * 2;

  {
    const u16* src = Vg + (size_t)kv2 * D + h * 128 + ch * 8;
    s16x8 a0 = *(const s16x8*)src;
    s16x8 a1 = *(const s16x8*)(src + D);
#pragma unroll
    for (int it = 0; it < 2; ++it) {
      int id = it * 512 + t;
      int kv = id >> 4, c0 = id & 15;
      gload_lds16(Kg + (size_t)kv * D + h * 128 + ((c0 ^ (kv & 7)) << 3), &Ks[0][id * 8]);
    }
#pragma unroll
    for (int jj = 0; jj < 8; ++jj) {
      int d = ch * 8 + jj;
      int sw = ((ch ^ jj) & 7) << 3;
      unsigned pr = (unsigned)(u16)a0[jj] | ((unsigned)(u16)a1[jj] << 16);
      *(unsigned*)&Vt[0][d * 64 + (kv2 ^ sw)] = pr;
    }
  }

  for (int kt = 0; kt < ntiles; ++kt) {
    const int b = kt & 1;
    const int kv0 = kt * 64;
    __syncthreads();

    s16x8 a0, a1;
    const bool pf = (kt + 1 < ntiles);
    if (pf) {
      const u16* src = Vg + (size_t)(kv0 + 64 + kv2) * D + h * 128 + ch * 8;
      a0 = *(const s16x8*)src;
      a1 = *(const s16x8*)(src + D);
#pragma unroll
      for (int it = 0; it < 2; ++it) {
        int id = it * 512 + t;
        int kv = id >> 4, c0 = id & 15;
        gload_lds16(Kg + (size_t)(kv0 + 64 + kv) * D + h * 128 + ((c0 ^ (kv & 7)) << 3),
                    &Ks[b ^ 1][id * 8]);
      }
    }

    if (kv0 <= qw0 + 15) {
      const bool masked = (kv0 + 63 > qw0);

      f32x4 st[4] = {};
      __builtin_amdgcn_s_setprio(1);
#pragma unroll
      for (int nt = 0; nt < 4; ++nt) {
        int kv = nt * 16 + lr;
        int sw = kv & 7;
#pragma unroll
        for (int kc = 0; kc < 4; ++kc) {
          s16x8 kf = *(const s16x8*)&Ks[b][kv * 128 + (((4 * kc + lk) ^ sw) << 3)];
          st[nt] = __builtin_amdgcn_mfma_f32_16x16x32_bf16(qf[kc], kf, st[nt], 0, 0, 0);
        }
      }
      __builtin_amdgcn_s_setprio(0);

      float pmax_[4];
#pragma unroll
      for (int r = 0; r < 4; ++r) {
        int q_r = qw0 + lk * 4 + r;
        if (masked) {
#pragma unroll
          for (int nt = 0; nt < 4; ++nt) {
            float sv = st[nt][r] * scale2;
            if (kv0 + nt * 16 + lr > q_r) sv = -1e30f;
            st[nt][r] = sv;
          }
        } else {
#pragma unroll
          for (int nt = 0; nt < 4; ++nt) st[nt][r] *= scale2;
        }
        float pm = fmaxf(fmaxf(st[0][r], st[1][r]), fmaxf(st[2][r], st[3][r]));
        pm = fmaxf(pm, __shfl_xor(pm, 1));
        pm = fmaxf(pm, __shfl_xor(pm, 2));
        pm = fmaxf(pm, __shfl_xor(pm, 4));
        pm = fmaxf(pm, __shfl_xor(pm, 8));
        pmax_[r] = pm;
      }
      bool nr = (pmax_[0] > m_r[0] + 8.f) || (pmax_[1] > m_r[1] + 8.f) ||
                (pmax_[2] > m_r[2] + 8.f) || (pmax_[3] > m_r[3] + 8.f);
      if (__any(nr)) {
#pragma unroll
        for (int r = 0; r < 4; ++r) {
          float mn = fmaxf(m_r[r], pmax_[r]);
          float al = __builtin_amdgcn_exp2f(m_r[r] - mn);
          m_r[r] = mn; l_r[r] *= al;
#pragma unroll
          for (int nb = 0; nb < 8; ++nb) o[nb][r] *= al;
        }
      }
#pragma unroll
      for (int r = 0; r < 4; ++r) {
        int ql = lk * 4 + r;
        int swp = ((ql >> 1) & 7) << 3;
        float ps = 0.f;
#pragma unroll
        for (int nt = 0; nt < 4; ++nt) {
          float pv = __builtin_amdgcn_exp2f(st[nt][r] - m_r[r]);
          ps += pv;
          Ps[wid][ql * 64 + ((nt * 16 + lr) ^ swp)] = f2bf(pv);
        }
        ps += __shfl_xor(ps, 1);
        ps += __shfl_xor(ps, 2);
        ps += __shfl_xor(ps, 4);
        ps += __shfl_xor(ps, 8);
        l_r[r] += ps;
      }
      asm volatile("s_waitcnt lgkmcnt(0)" ::: "memory");

      s16x8 pa[2];
#pragma unroll
      for (int ks = 0; ks < 2; ++ks) {
        int col = (ks * 32 + lk * 8) ^ (((lr >> 1) & 7) << 3);
        pa[ks] = *(const s16x8*)&Ps[wid][lr * 64 + col];
      }

      __builtin_amdgcn_s_setprio(1);
#pragma unroll
      for (int ks = 0; ks < 2; ++ks) {
#pragma unroll
        for (int nb = 0; nb < 8; ++nb) {
          int d = nb * 16 + lr;
          int g = (((d >> 3) ^ d) & 7) << 3;
          s16x8 vf = *(const s16x8*)&Vt[b][d * 64 + ((ks * 32 + lk * 8) ^ g)];
          o[nb] = __builtin_amdgcn_mfma_f32_16x16x32_bf16(pa[ks], vf, o[nb], 0, 0, 0);
        }
      }
      __builtin_amdgcn_s_setprio(0);
    }

    if (pf) {
#pragma unroll
      for (int jj = 0; jj < 8; ++jj) {
        int d = ch * 8 + jj;
        int sw = ((ch ^ jj) & 7) << 3;
        unsigned pr = (unsigned)(u16)a0[jj] | ((unsigned)(u16)a1[jj] << 16);
        *(unsigned*)&Vt[b ^ 1][d * 64 + (kv2 ^ sw)] = pr;
      }
    }
  }

#pragma unroll
  for (int r = 0; r < 4; ++r) {
    float inv = 1.f / l_r[r];
    int q_r = qw0 + lk * 4 + r;
#pragma unroll
    for (int nb = 0; nb < 8; ++nb)
      Ctx[(size_t)q_r * D + h * 128 + nb * 16 + lr] = f2bf(o[nb][r] * inv);
  }
}

// ---------------- launcher ----------------
extern "C" void kernel_launch(void* const* d_in, const int* in_sizes, int n_in,
                              void* d_out, int out_size, void* d_ws, size_t ws_size,
                              hipStream_t stream) {
  const int S = 2048, D = 4096, H = 32;
  const size_t SD = (size_t)S * D, DD = (size_t)D * D;

  const float* X  = (const float*)d_in[0];
  const float* Wq = (const float*)d_in[1];
  const float* Wk = (const float*)d_in[2];
  const float* Wv = (const float*)d_in[3];
  const float* Wo = (const float*)d_in[4];
  const float* bo = (const float*)d_in[5];
  const float* cs = (const float*)d_in[6];
  const float* sn = (const float*)d_in[7];

  u16* WB = (u16*)d_ws;
  u16* Xb = WB + DD;
  u16* Qb = Xb + SD;
  u16* Kb = Qb + SD;
  u16* Vb = Kb + SD;

  dim3 blk(256);
  dim3 g2(256);      // (2048/128) x (4096/256)
  dim3 b2(512);

  cvt_f32_bf16<<<(int)(SD / 1024), blk, 0, stream>>>(X, Xb, (int)SD);
  cvt_f32_bf16<<<(int)(DD / 1024), blk, 0, stream>>>(Wq, WB, (int)DD);
  gemm_bt2<u16, false><<<g2, b2, 0, stream>>>(Xb, WB, Qb, nullptr, S, D, D);
  cvt_f32_bf16<<<(int)(DD / 1024), blk, 0, stream>>>(Wk, WB, (int)DD);
  gemm_bt2<u16, false><<<g2, b2, 0, stream>>>(Xb, WB, Kb, nullptr, S, D, D);
  cvt_f32_bf16<<<(int)(DD / 1024), blk, 0, stream>>>(Wv, WB, (int)DD);
  gemm_bt2<u16, false><<<g2, b2, 0, stream>>>(Xb, WB, Vb, nullptr, S, D, D);

  rope_qk<<<(S * H * 64) / 256, blk, 0, stream>>>(Qb, Kb, cs, sn);

  flash_attn<<<dim3(512), dim3(512), 0, stream>>>(Qb, Kb, Vb, Xb /*Ctx*/);

  cvt_f32_bf16<<<(int)(DD / 1024), blk, 0, stream>>>(Wo, WB, (int)DD);
  gemm_bt2<float, true><<<g2, b2, 0, stream>>>(Xb, WB, (float*)d_out, bo, S, D, D);
}

// Round 7
// 578.373 us; speedup vs baseline: 1.0695x; 1.0695x over previous
//
#include <hip/hip_runtime.h>

typedef unsigned short u16;
typedef __attribute__((ext_vector_type(8))) short s16x8;
typedef __attribute__((ext_vector_type(4))) float f32x4;

__device__ __forceinline__ u16 f2bf(float f) {
  unsigned u = __float_as_uint(f);
  u += 0x7fffu + ((u >> 16) & 1u);   // RNE
  return (u16)(u >> 16);
}
__device__ __forceinline__ float bf2f(u16 h) {
  return __uint_as_float(((unsigned)h) << 16);
}

typedef __attribute__((address_space(1))) const void gvoid_t;
typedef __attribute__((address_space(3))) void lvoid_t;
__device__ __forceinline__ void gload_lds16(const void* g, void* l) {
  __builtin_amdgcn_global_load_lds((gvoid_t*)g, (lvoid_t*)l, 16, 0, 0);
}

// ---------------- f32 -> bf16 convert (vectorized) ----------------
__global__ void cvt_f32_bf16(const float* __restrict__ in, u16* __restrict__ out, int n) {
  int i = (blockIdx.x * 256 + threadIdx.x) * 4;
  if (i >= n) return;
  float4 v = *(const float4*)(in + i);
  ushort4 o;
  o.x = f2bf(v.x); o.y = f2bf(v.y); o.z = f2bf(v.z); o.w = f2bf(v.w);
  *(ushort4*)(out + i) = o;
}

// ---------------- GEMM v4: C[M,N] = A[M,K]*B[N,K]^T ----------------
// m97-family with max co-residency: 128x128 tile, BK=32, 256 thr (4 waves
// 2x2, wave=64x64), TRIPLE-buffered 48KB LDS -> 3 blocks/CU, counted
// vmcnt(4) (never 0 mid-loop), ONE barrier per K-tile. Cross-block overlap
// covers barrier drains (m114/m97 mechanism) instead of intra-block phases.
template<typename OutT, bool BIAS>
__global__ __launch_bounds__(256) void gemm_bt3(
    const u16* __restrict__ A, const u16* __restrict__ Bm,
    OutT* __restrict__ C, const float* __restrict__ bias,
    int M, int N, int K)
{
  __shared__ u16 As[3][128 * 32];
  __shared__ u16 Bs[3][128 * 32];

  const int t = threadIdx.x;
  const int lane = t & 63, wid = t >> 6;
  const int wm = wid >> 1, wn = wid & 1;
  const int lr = lane & 15, lk = lane >> 4;

  // XCD map: 512 blocks = 8 XCD x (16 m-blocks x 4 n-blocks).
  // Per-XCD B-panel = 4 x 128 x 4096 x 2B = 4MB -> L2-resident.
  const int wg = blockIdx.x;
  const int xcd = wg & 7, j = wg >> 3;           // j 0..63
  const int m0 = (j & 15) * 128;
  const int n0 = ((xcd << 2) | (j >> 4)) * 128;

  const int nt = K >> 5;                          // 128 K-tiles

  f32x4 acc[4][4] = {};

  // stage K-tile KT: A,B each 128 rows x 4 chunks(16B); 2 gloads/thread each.
  // swizzle: store chunk c0 holds global chunk c0 ^ ((row>>1)&3)  (involution)
#define STAGE3(KT)                                                             \
  {                                                                            \
    const int bu_ = (KT) % 3;                                                  \
    const int k0_ = (KT) << 5;                                                 \
    _Pragma("unroll")                                                          \
    for (int it = 0; it < 2; ++it) {                                           \
      int id = it * 256 + t;                                                   \
      int r = id >> 2, c0 = id & 3;                                            \
      int cs = (c0 ^ ((r >> 1) & 3)) << 3;                                     \
      gload_lds16(A + (size_t)(m0 + r) * K + k0_ + cs, &As[bu_][id * 8]);      \
      gload_lds16(Bm + (size_t)(n0 + r) * K + k0_ + cs, &Bs[bu_][id * 8]);     \
    }                                                                          \
  }

  // prologue: tiles 0,1 in flight (8 loads); vmcnt(4) -> tile 0 landed
  STAGE3(0);
  STAGE3(1);
  asm volatile("s_waitcnt vmcnt(4)" ::: "memory");
  __builtin_amdgcn_s_barrier();

  for (int kt = 0; kt < nt; ++kt) {
    const int bu = kt % 3;
    if (kt + 2 < nt) STAGE3(kt + 2);

    s16x8 af[4], bf[4];
#pragma unroll
    for (int i = 0; i < 4; ++i) {
      int ra = wm * 64 + i * 16 + lr;
      af[i] = *(const s16x8*)&As[bu][ra * 32 + ((lk ^ ((ra >> 1) & 3)) << 3)];
      int rb = wn * 64 + i * 16 + lr;
      bf[i] = *(const s16x8*)&Bs[bu][rb * 32 + ((lk ^ ((rb >> 1) & 3)) << 3)];
    }
    __builtin_amdgcn_s_setprio(1);
#pragma unroll
    for (int i = 0; i < 4; ++i)
#pragma unroll
      for (int jn = 0; jn < 4; ++jn)
        acc[i][jn] = __builtin_amdgcn_mfma_f32_16x16x32_bf16(af[i], bf[jn], acc[i][jn], 0, 0, 0);
    __builtin_amdgcn_s_setprio(0);

    // boundary: own ds_reads done; counted vmcnt -> kt+1 landed, kt+2 may fly
    asm volatile("s_waitcnt lgkmcnt(0)" ::: "memory");
    if (kt + 2 < nt)       { asm volatile("s_waitcnt vmcnt(4)" ::: "memory"); }
    else if (kt + 2 == nt) { asm volatile("s_waitcnt vmcnt(0)" ::: "memory"); }
    if (kt + 1 < nt) __builtin_amdgcn_s_barrier();
  }
#undef STAGE3

  // epilogue: D layout col=lane&15 (B-row), row=(lane>>4)*4+reg (A-row)
#pragma unroll
  for (int i = 0; i < 4; ++i) {
    int row_b = m0 + wm * 64 + i * 16 + lk * 4;
#pragma unroll
    for (int jn = 0; jn < 4; ++jn) {
      int col = n0 + wn * 64 + jn * 16 + lr;
      float bv = BIAS ? bias[col] : 0.f;
#pragma unroll
      for (int r = 0; r < 4; ++r) {
        float v = acc[i][jn][r] + bv;
        size_t off = (size_t)(row_b + r) * N + col;
        if constexpr (sizeof(OutT) == 2) ((u16*)C)[off] = f2bf(v);
        else                             ((float*)C)[off] = v;
      }
    }
  }
}

// ---------------- RoPE on Q and K in place (bf16) ----------------
__global__ void rope_qk(u16* __restrict__ Q, u16* __restrict__ Kt,
                        const float* __restrict__ cosp, const float* __restrict__ sinp) {
  int i = blockIdx.x * 256 + threadIdx.x;   // over S*H*64
  int d = i & 63;
  int h = (i >> 6) & 31;
  int s = i >> 11;
  float c = cosp[s * 128 + d], sn = sinp[s * 128 + d];
  size_t base = (size_t)s * 4096 + h * 128 + d;
  float q1 = bf2f(Q[base]), q2 = bf2f(Q[base + 64]);
  Q[base]      = f2bf(q1 * c - q2 * sn);
  Q[base + 64] = f2bf(q2 * c + q1 * sn);
  float k1 = bf2f(Kt[base]), k2 = bf2f(Kt[base + 64]);
  Kt[base]      = f2bf(k1 * c - k2 * sn);
  Kt[base + 64] = f2bf(k2 * c + k1 * sn);
}

// ---------------- Flash attention (causal): QBLK=128, KVBLK=64, 8 waves ----------------
__global__ __launch_bounds__(512) void flash_attn(
    const u16* __restrict__ Q, const u16* __restrict__ Kg, const u16* __restrict__ Vg,
    u16* __restrict__ Ctx)
{
  const int D = 4096;
  __shared__ u16 Ks[2][64 * 128];  // [kv][d-chunk], chunk XOR-swizzled by (kv&7)
  __shared__ u16 Vt[2][128 * 64];  // [d][kv], kv XOR-swizzled by (((d>>3)^d)&7)<<3
  __shared__ u16 Ps[8][16 * 64];   // per-wave P, col XOR-swizzled by ((q>>1)&7)<<3

  const int t = threadIdx.x, lane = t & 63, wid = t >> 6;
  const int lr = lane & 15, lk = lane >> 4;

  const int wg = blockIdx.x;              // 0..511
  const int xcd = wg & 7, j = wg >> 3;    // j 0..63 local
  const int bx = 15 - (j >> 2);           // LPT: longest first
  const int h = xcd * 4 + (j & 3);        // 4 heads per XCD
  const int q0 = bx * 128;
  const int qw0 = q0 + wid * 16;

  s16x8 qf[4];
#pragma unroll
  for (int kc = 0; kc < 4; ++kc)
    qf[kc] = *(const s16x8*)(Q + (size_t)(qw0 + lr) * D + h * 128 + kc * 32 + lk * 8);

  f32x4 o[8] = {};
  float m_r[4] = {-1e30f, -1e30f, -1e30f, -1e30f};
  float l_r[4] = {0.f, 0.f, 0.f, 0.f};

  const int ntiles = 2 * bx + 2;
  const float scale2 = 0.12751779f;       // (1/sqrt(128)) * log2(e)

  const int ch = t & 15, kv2 = (t >> 4) * 2;

  {
    const u16* src = Vg + (size_t)kv2 * D + h * 128 + ch * 8;
    s16x8 a0 = *(const s16x8*)src;
    s16x8 a1 = *(const s16x8*)(src + D);
#pragma unroll
    for (int it = 0; it < 2; ++it) {
      int id = it * 512 + t;
      int kv = id >> 4, c0 = id & 15;
      gload_lds16(Kg + (size_t)kv * D + h * 128 + ((c0 ^ (kv & 7)) << 3), &Ks[0][id * 8]);
    }
#pragma unroll
    for (int jj = 0; jj < 8; ++jj) {
      int d = ch * 8 + jj;
      int sw = ((ch ^ jj) & 7) << 3;
      unsigned pr = (unsigned)(u16)a0[jj] | ((unsigned)(u16)a1[jj] << 16);
      *(unsigned*)&Vt[0][d * 64 + (kv2 ^ sw)] = pr;
    }
  }

  for (int kt = 0; kt < ntiles; ++kt) {
    const int b = kt & 1;
    const int kv0 = kt * 64;
    __syncthreads();

    s16x8 a0, a1;
    const bool pf = (kt + 1 < ntiles);
    if (pf) {
      const u16* src = Vg + (size_t)(kv0 + 64 + kv2) * D + h * 128 + ch * 8;
      a0 = *(const s16x8*)src;
      a1 = *(const s16x8*)(src + D);
#pragma unroll
      for (int it = 0; it < 2; ++it) {
        int id = it * 512 + t;
        int kv = id >> 4, c0 = id & 15;
        gload_lds16(Kg + (size_t)(kv0 + 64 + kv) * D + h * 128 + ((c0 ^ (kv & 7)) << 3),
                    &Ks[b ^ 1][id * 8]);
      }
    }

    if (kv0 <= qw0 + 15) {
      const bool masked = (kv0 + 63 > qw0);

      f32x4 st[4] = {};
      __builtin_amdgcn_s_setprio(1);
#pragma unroll
      for (int nt = 0; nt < 4; ++nt) {
        int kv = nt * 16 + lr;
        int sw = kv & 7;
#pragma unroll
        for (int kc = 0; kc < 4; ++kc) {
          s16x8 kf = *(const s16x8*)&Ks[b][kv * 128 + (((4 * kc + lk) ^ sw) << 3)];
          st[nt] = __builtin_amdgcn_mfma_f32_16x16x32_bf16(qf[kc], kf, st[nt], 0, 0, 0);
        }
      }
      __builtin_amdgcn_s_setprio(0);

      float pmax_[4];
#pragma unroll
      for (int r = 0; r < 4; ++r) {
        int q_r = qw0 + lk * 4 + r;
        if (masked) {
#pragma unroll
          for (int nt = 0; nt < 4; ++nt) {
            float sv = st[nt][r] * scale2;
            if (kv0 + nt * 16 + lr > q_r) sv = -1e30f;
            st[nt][r] = sv;
          }
        } else {
#pragma unroll
          for (int nt = 0; nt < 4; ++nt) st[nt][r] *= scale2;
        }
        float pm = fmaxf(fmaxf(st[0][r], st[1][r]), fmaxf(st[2][r], st[3][r]));
        pm = fmaxf(pm, __shfl_xor(pm, 1));
        pm = fmaxf(pm, __shfl_xor(pm, 2));
        pm = fmaxf(pm, __shfl_xor(pm, 4));
        pm = fmaxf(pm, __shfl_xor(pm, 8));
        pmax_[r] = pm;
      }
      bool nr = (pmax_[0] > m_r[0] + 8.f) || (pmax_[1] > m_r[1] + 8.f) ||
                (pmax_[2] > m_r[2] + 8.f) || (pmax_[3] > m_r[3] + 8.f);
      if (__any(nr)) {
#pragma unroll
        for (int r = 0; r < 4; ++r) {
          float mn = fmaxf(m_r[r], pmax_[r]);
          float al = __builtin_amdgcn_exp2f(m_r[r] - mn);
          m_r[r] = mn; l_r[r] *= al;
#pragma unroll
          for (int nb = 0; nb < 8; ++nb) o[nb][r] *= al;
        }
      }
#pragma unroll
      for (int r = 0; r < 4; ++r) {
        int ql = lk * 4 + r;
        int swp = ((ql >> 1) & 7) << 3;
        float ps = 0.f;
#pragma unroll
        for (int nt = 0; nt < 4; ++nt) {
          float pv = __builtin_amdgcn_exp2f(st[nt][r] - m_r[r]);
          ps += pv;
          Ps[wid][ql * 64 + ((nt * 16 + lr) ^ swp)] = f2bf(pv);
        }
        ps += __shfl_xor(ps, 1);
        ps += __shfl_xor(ps, 2);
        ps += __shfl_xor(ps, 4);
        ps += __shfl_xor(ps, 8);
        l_r[r] += ps;
      }
      asm volatile("s_waitcnt lgkmcnt(0)" ::: "memory");

      s16x8 pa[2];
#pragma unroll
      for (int ks = 0; ks < 2; ++ks) {
        int col = (ks * 32 + lk * 8) ^ (((lr >> 1) & 7) << 3);
        pa[ks] = *(const s16x8*)&Ps[wid][lr * 64 + col];
      }

      __builtin_amdgcn_s_setprio(1);
#pragma unroll
      for (int ks = 0; ks < 2; ++ks) {
#pragma unroll
        for (int nb = 0; nb < 8; ++nb) {
          int d = nb * 16 + lr;
          int g = (((d >> 3) ^ d) & 7) << 3;
          s16x8 vf = *(const s16x8*)&Vt[b][d * 64 + ((ks * 32 + lk * 8) ^ g)];
          o[nb] = __builtin_amdgcn_mfma_f32_16x16x32_bf16(pa[ks], vf, o[nb], 0, 0, 0);
        }
      }
      __builtin_amdgcn_s_setprio(0);
    }

    if (pf) {
#pragma unroll
      for (int jj = 0; jj < 8; ++jj) {
        int d = ch * 8 + jj;
        int sw = ((ch ^ jj) & 7) << 3;
        unsigned pr = (unsigned)(u16)a0[jj] | ((unsigned)(u16)a1[jj] << 16);
        *(unsigned*)&Vt[b ^ 1][d * 64 + (kv2 ^ sw)] = pr;
      }
    }
  }

#pragma unroll
  for (int r = 0; r < 4; ++r) {
    float inv = 1.f / l_r[r];
    int q_r = qw0 + lk * 4 + r;
#pragma unroll
    for (int nb = 0; nb < 8; ++nb)
      Ctx[(size_t)q_r * D + h * 128 + nb * 16 + lr] = f2bf(o[nb][r] * inv);
  }
}

// ---------------- launcher ----------------
extern "C" void kernel_launch(void* const* d_in, const int* in_sizes, int n_in,
                              void* d_out, int out_size, void* d_ws, size_t ws_size,
                              hipStream_t stream) {
  const int S = 2048, D = 4096, H = 32;
  const size_t SD = (size_t)S * D, DD = (size_t)D * D;

  const float* X  = (const float*)d_in[0];
  const float* Wq = (const float*)d_in[1];
  const float* Wk = (const float*)d_in[2];
  const float* Wv = (const float*)d_in[3];
  const float* Wo = (const float*)d_in[4];
  const float* bo = (const float*)d_in[5];
  const float* cs = (const float*)d_in[6];
  const float* sn = (const float*)d_in[7];

  u16* WB = (u16*)d_ws;
  u16* Xb = WB + DD;
  u16* Qb = Xb + SD;
  u16* Kb = Qb + SD;
  u16* Vb = Kb + SD;

  dim3 blk(256);
  dim3 g3(512);      // 8 XCD x 16 m x 4 n   (128x128 tiles)
  dim3 b3(256);

  cvt_f32_bf16<<<(int)(SD / 1024), blk, 0, stream>>>(X, Xb, (int)SD);
  cvt_f32_bf16<<<(int)(DD / 1024), blk, 0, stream>>>(Wq, WB, (int)DD);
  gemm_bt3<u16, false><<<g3, b3, 0, stream>>>(Xb, WB, Qb, nullptr, S, D, D);
  cvt_f32_bf16<<<(int)(DD / 1024), blk, 0, stream>>>(Wk, WB, (int)DD);
  gemm_bt3<u16, false><<<g3, b3, 0, stream>>>(Xb, WB, Kb, nullptr, S, D, D);
  cvt_f32_bf16<<<(int)(DD / 1024), blk, 0, stream>>>(Wv, WB, (int)DD);
  gemm_bt3<u16, false><<<g3, b3, 0, stream>>>(Xb, WB, Vb, nullptr, S, D, D);

  rope_qk<<<(S * H * 64) / 256, blk, 0, stream>>>(Qb, Kb, cs, sn);

  flash_attn<<<dim3(512), dim3(512), 0, stream>>>(Qb, Kb, Vb, Xb /*Ctx*/);

  cvt_f32_bf16<<<(int)(DD / 1024), blk, 0, stream>>>(Wo, WB, (int)DD);
  gemm_bt3<float, true><<<g3, b3, 0, stream>>>(Xb, WB, (float*)d_out, bo, S, D, D);
}

// Round 8
// 574.248 us; speedup vs baseline: 1.0772x; 1.0072x over previous
//
#include <hip/hip_runtime.h>

typedef unsigned short u16;
typedef __attribute__((ext_vector_type(8))) short s16x8;
typedef __attribute__((ext_vector_type(4))) float f32x4;

__device__ __forceinline__ u16 f2bf(float f) {
  unsigned u = __float_as_uint(f);
  u += 0x7fffu + ((u >> 16) & 1u);   // RNE
  return (u16)(u >> 16);
}
__device__ __forceinline__ float bf2f(u16 h) {
  return __uint_as_float(((unsigned)h) << 16);
}

typedef __attribute__((address_space(1))) const void gvoid_t;
typedef __attribute__((address_space(3))) void lvoid_t;
__device__ __forceinline__ void gload_lds16(const void* g, void* l) {
  __builtin_amdgcn_global_load_lds((gvoid_t*)g, (lvoid_t*)l, 16, 0, 0);
}

// ---------------- f32 -> bf16 convert (vectorized) ----------------
__global__ void cvt_f32_bf16(const float* __restrict__ in, u16* __restrict__ out, int n) {
  int i = (blockIdx.x * 256 + threadIdx.x) * 4;
  if (i >= n) return;
  float4 v = *(const float4*)(in + i);
  ushort4 o;
  o.x = f2bf(v.x); o.y = f2bf(v.y); o.z = f2bf(v.z); o.w = f2bf(v.w);
  *(ushort4*)(out + i) = o;
}

// ---------------- GEMM v4: C[M,N] = A[M,K]*B[N,K]^T ----------------
// 128x128 tile, BK=32, 256 thr (4 waves 2x2), triple-buffered 48KB LDS
// -> 3 blocks/CU, counted vmcnt(4), one barrier per K-tile.
template<typename OutT, bool BIAS>
__global__ __launch_bounds__(256) void gemm_bt3(
    const u16* __restrict__ A, const u16* __restrict__ Bm,
    OutT* __restrict__ C, const float* __restrict__ bias,
    int M, int N, int K)
{
  __shared__ u16 As[3][128 * 32];
  __shared__ u16 Bs[3][128 * 32];

  const int t = threadIdx.x;
  const int lane = t & 63, wid = t >> 6;
  const int wm = wid >> 1, wn = wid & 1;
  const int lr = lane & 15, lk = lane >> 4;

  const int wg = blockIdx.x;
  const int xcd = wg & 7, j = wg >> 3;           // j 0..63
  const int m0 = (j & 15) * 128;
  const int n0 = ((xcd << 2) | (j >> 4)) * 128;

  const int nt = K >> 5;

  f32x4 acc[4][4] = {};

#define STAGE3(KT)                                                             \
  {                                                                            \
    const int bu_ = (KT) % 3;                                                  \
    const int k0_ = (KT) << 5;                                                 \
    _Pragma("unroll")                                                          \
    for (int it = 0; it < 2; ++it) {                                           \
      int id = it * 256 + t;                                                   \
      int r = id >> 2, c0 = id & 3;                                            \
      int cs = (c0 ^ ((r >> 1) & 3)) << 3;                                     \
      gload_lds16(A + (size_t)(m0 + r) * K + k0_ + cs, &As[bu_][id * 8]);      \
      gload_lds16(Bm + (size_t)(n0 + r) * K + k0_ + cs, &Bs[bu_][id * 8]);     \
    }                                                                          \
  }

  STAGE3(0);
  STAGE3(1);
  asm volatile("s_waitcnt vmcnt(4)" ::: "memory");
  __builtin_amdgcn_s_barrier();

  for (int kt = 0; kt < nt; ++kt) {
    const int bu = kt % 3;
    if (kt + 2 < nt) STAGE3(kt + 2);

    s16x8 af[4], bf[4];
#pragma unroll
    for (int i = 0; i < 4; ++i) {
      int ra = wm * 64 + i * 16 + lr;
      af[i] = *(const s16x8*)&As[bu][ra * 32 + ((lk ^ ((ra >> 1) & 3)) << 3)];
      int rb = wn * 64 + i * 16 + lr;
      bf[i] = *(const s16x8*)&Bs[bu][rb * 32 + ((lk ^ ((rb >> 1) & 3)) << 3)];
    }
    __builtin_amdgcn_s_setprio(1);
#pragma unroll
    for (int i = 0; i < 4; ++i)
#pragma unroll
      for (int jn = 0; jn < 4; ++jn)
        acc[i][jn] = __builtin_amdgcn_mfma_f32_16x16x32_bf16(af[i], bf[jn], acc[i][jn], 0, 0, 0);
    __builtin_amdgcn_s_setprio(0);

    asm volatile("s_waitcnt lgkmcnt(0)" ::: "memory");
    if (kt + 2 < nt)       { asm volatile("s_waitcnt vmcnt(4)" ::: "memory"); }
    else if (kt + 2 == nt) { asm volatile("s_waitcnt vmcnt(0)" ::: "memory"); }
    if (kt + 1 < nt) __builtin_amdgcn_s_barrier();
  }
#undef STAGE3

#pragma unroll
  for (int i = 0; i < 4; ++i) {
    int row_b = m0 + wm * 64 + i * 16 + lk * 4;
#pragma unroll
    for (int jn = 0; jn < 4; ++jn) {
      int col = n0 + wn * 64 + jn * 16 + lr;
      float bv = BIAS ? bias[col] : 0.f;
#pragma unroll
      for (int r = 0; r < 4; ++r) {
        float v = acc[i][jn][r] + bv;
        size_t off = (size_t)(row_b + r) * N + col;
        if constexpr (sizeof(OutT) == 2) ((u16*)C)[off] = f2bf(v);
        else                             ((float*)C)[off] = v;
      }
    }
  }
}

// ---------------- RoPE on Q and K in place (bf16) ----------------
__global__ void rope_qk(u16* __restrict__ Q, u16* __restrict__ Kt,
                        const float* __restrict__ cosp, const float* __restrict__ sinp) {
  int i = blockIdx.x * 256 + threadIdx.x;   // over S*H*64
  int d = i & 63;
  int h = (i >> 6) & 31;
  int s = i >> 11;
  float c = cosp[s * 128 + d], sn = sinp[s * 128 + d];
  size_t base = (size_t)s * 4096 + h * 128 + d;
  float q1 = bf2f(Q[base]), q2 = bf2f(Q[base + 64]);
  Q[base]      = f2bf(q1 * c - q2 * sn);
  Q[base + 64] = f2bf(q2 * c + q1 * sn);
  float k1 = bf2f(Kt[base]), k2 = bf2f(Kt[base + 64]);
  Kt[base]      = f2bf(k1 * c - k2 * sn);
  Kt[base + 64] = f2bf(k2 * c + k1 * sn);
}

// ---------------- Flash attention (causal): QBLK=128, KVBLK=64, 8 waves ----------------
// 64KB LDS (K dbuf + SINGLE Vt + Ps) -> 2 blocks/CU; raw s_barrier before
// the Vt rewrite keeps K-prefetch in flight (no vmcnt drain).
__global__ __launch_bounds__(512) void flash_attn(
    const u16* __restrict__ Q, const u16* __restrict__ Kg, const u16* __restrict__ Vg,
    u16* __restrict__ Ctx)
{
  const int D = 4096;
  __shared__ u16 Ks[2][64 * 128];  // [kv][d-chunk], chunk XOR-swizzled by (kv&7)
  __shared__ u16 Vt[128 * 64];     // [d][kv], kv XOR-swizzled by (((d>>3)^d)&7)<<3
  __shared__ u16 Ps[8][16 * 64];   // per-wave P, col XOR-swizzled by ((q>>1)&7)<<3

  const int t = threadIdx.x, lane = t & 63, wid = t >> 6;
  const int lr = lane & 15, lk = lane >> 4;

  const int wg = blockIdx.x;              // 0..511
  const int xcd = wg & 7, j = wg >> 3;    // j 0..63 local
  const int bx = 15 - (j >> 2);           // LPT: longest first
  const int h = xcd * 4 + (j & 3);        // 4 heads per XCD
  const int q0 = bx * 128;
  const int qw0 = q0 + wid * 16;

  s16x8 qf[4];
#pragma unroll
  for (int kc = 0; kc < 4; ++kc)
    qf[kc] = *(const s16x8*)(Q + (size_t)(qw0 + lr) * D + h * 128 + kc * 32 + lk * 8);

  f32x4 o[8] = {};
  float m_r[4] = {-1e30f, -1e30f, -1e30f, -1e30f};
  float l_r[4] = {0.f, 0.f, 0.f, 0.f};

  const int ntiles = 2 * bx + 2;
  const float scale2 = 0.12751779f;       // (1/sqrt(128)) * log2(e)

  const int ch = t & 15, kv2 = (t >> 4) * 2;

  // prologue: K(0) gloads; V(0) regs -> Vt (visible after first barrier)
  {
    const u16* src = Vg + (size_t)kv2 * D + h * 128 + ch * 8;
    s16x8 a0 = *(const s16x8*)src;
    s16x8 a1 = *(const s16x8*)(src + D);
#pragma unroll
    for (int it = 0; it < 2; ++it) {
      int id = it * 512 + t;
      int kv = id >> 4, c0 = id & 15;
      gload_lds16(Kg + (size_t)kv * D + h * 128 + ((c0 ^ (kv & 7)) << 3), &Ks[0][id * 8]);
    }
#pragma unroll
    for (int jj = 0; jj < 8; ++jj) {
      int d = ch * 8 + jj;
      int sw = ((ch ^ jj) & 7) << 3;
      unsigned pr = (unsigned)(u16)a0[jj] | ((unsigned)(u16)a1[jj] << 16);
      *(unsigned*)&Vt[d * 64 + (kv2 ^ sw)] = pr;
    }
  }

  for (int kt = 0; kt < ntiles; ++kt) {
    const int b = kt & 1;
    const int kv0 = kt * 64;
    __syncthreads();   // K(kt) landed (vmcnt drain), Vt(kt) visible

    s16x8 a0, a1;
    const bool pf = (kt + 1 < ntiles);
    if (pf) {
      const u16* src = Vg + (size_t)(kv0 + 64 + kv2) * D + h * 128 + ch * 8;
      a0 = *(const s16x8*)src;
      a1 = *(const s16x8*)(src + D);
#pragma unroll
      for (int it = 0; it < 2; ++it) {
        int id = it * 512 + t;
        int kv = id >> 4, c0 = id & 15;
        gload_lds16(Kg + (size_t)(kv0 + 64 + kv) * D + h * 128 + ((c0 ^ (kv & 7)) << 3),
                    &Ks[b ^ 1][id * 8]);
      }
    }

    if (kv0 <= qw0 + 15) {
      const bool masked = (kv0 + 63 > qw0);

      f32x4 st[4] = {};
      __builtin_amdgcn_s_setprio(1);
#pragma unroll
      for (int nt = 0; nt < 4; ++nt) {
        int kv = nt * 16 + lr;
        int sw = kv & 7;
#pragma unroll
        for (int kc = 0; kc < 4; ++kc) {
          s16x8 kf = *(const s16x8*)&Ks[b][kv * 128 + (((4 * kc + lk) ^ sw) << 3)];
          st[nt] = __builtin_amdgcn_mfma_f32_16x16x32_bf16(qf[kc], kf, st[nt], 0, 0, 0);
        }
      }
      __builtin_amdgcn_s_setprio(0);

      float pmax_[4];
#pragma unroll
      for (int r = 0; r < 4; ++r) {
        int q_r = qw0 + lk * 4 + r;
        if (masked) {
#pragma unroll
          for (int nt = 0; nt < 4; ++nt) {
            float sv = st[nt][r] * scale2;
            if (kv0 + nt * 16 + lr > q_r) sv = -1e30f;
            st[nt][r] = sv;
          }
        } else {
#pragma unroll
          for (int nt = 0; nt < 4; ++nt) st[nt][r] *= scale2;
        }
        float pm = fmaxf(fmaxf(st[0][r], st[1][r]), fmaxf(st[2][r], st[3][r]));
        pm = fmaxf(pm, __shfl_xor(pm, 1));
        pm = fmaxf(pm, __shfl_xor(pm, 2));
        pm = fmaxf(pm, __shfl_xor(pm, 4));
        pm = fmaxf(pm, __shfl_xor(pm, 8));
        pmax_[r] = pm;
      }
      bool nr = (pmax_[0] > m_r[0] + 8.f) || (pmax_[1] > m_r[1] + 8.f) ||
                (pmax_[2] > m_r[2] + 8.f) || (pmax_[3] > m_r[3] + 8.f);
      if (__any(nr)) {
#pragma unroll
        for (int r = 0; r < 4; ++r) {
          float mn = fmaxf(m_r[r], pmax_[r]);
          float al = __builtin_amdgcn_exp2f(m_r[r] - mn);
          m_r[r] = mn; l_r[r] *= al;
#pragma unroll
          for (int nb = 0; nb < 8; ++nb) o[nb][r] *= al;
        }
      }
#pragma unroll
      for (int r = 0; r < 4; ++r) {
        int ql = lk * 4 + r;
        int swp = ((ql >> 1) & 7) << 3;
        float ps = 0.f;
#pragma unroll
        for (int nt = 0; nt < 4; ++nt) {
          float pv = __builtin_amdgcn_exp2f(st[nt][r] - m_r[r]);
          ps += pv;
          Ps[wid][ql * 64 + ((nt * 16 + lr) ^ swp)] = f2bf(pv);
        }
        ps += __shfl_xor(ps, 1);
        ps += __shfl_xor(ps, 2);
        ps += __shfl_xor(ps, 4);
        ps += __shfl_xor(ps, 8);
        l_r[r] += ps;
      }
      asm volatile("s_waitcnt lgkmcnt(0)" ::: "memory");

      s16x8 pa[2];
#pragma unroll
      for (int ks = 0; ks < 2; ++ks) {
        int col = (ks * 32 + lk * 8) ^ (((lr >> 1) & 7) << 3);
        pa[ks] = *(const s16x8*)&Ps[wid][lr * 64 + col];
      }

      __builtin_amdgcn_s_setprio(1);
#pragma unroll
      for (int ks = 0; ks < 2; ++ks) {
#pragma unroll
        for (int nb = 0; nb < 8; ++nb) {
          int d = nb * 16 + lr;
          int g = (((d >> 3) ^ d) & 7) << 3;
          s16x8 vf = *(const s16x8*)&Vt[d * 64 + ((ks * 32 + lk * 8) ^ g)];
          o[nb] = __builtin_amdgcn_mfma_f32_16x16x32_bf16(pa[ks], vf, o[nb], 0, 0, 0);
        }
      }
      __builtin_amdgcn_s_setprio(0);
    }

    if (pf) {
      // all waves finished PV reads of Vt; exec-only barrier (no vmcnt drain,
      // K(kt+1) gloads stay in flight), then overwrite Vt with V(kt+1).
      __builtin_amdgcn_s_barrier();
#pragma unroll
      for (int jj = 0; jj < 8; ++jj) {
        int d = ch * 8 + jj;
        int sw = ((ch ^ jj) & 7) << 3;
        unsigned pr = (unsigned)(u16)a0[jj] | ((unsigned)(u16)a1[jj] << 16);
        *(unsigned*)&Vt[d * 64 + (kv2 ^ sw)] = pr;
      }
    }
  }

#pragma unroll
  for (int r = 0; r < 4; ++r) {
    float inv = 1.f / l_r[r];
    int q_r = qw0 + lk * 4 + r;
#pragma unroll
    for (int nb = 0; nb < 8; ++nb)
      Ctx[(size_t)q_r * D + h * 128 + nb * 16 + lr] = f2bf(o[nb][r] * inv);
  }
}

// ---------------- launcher ----------------
extern "C" void kernel_launch(void* const* d_in, const int* in_sizes, int n_in,
                              void* d_out, int out_size, void* d_ws, size_t ws_size,
                              hipStream_t stream) {
  const int S = 2048, D = 4096, H = 32;
  const size_t SD = (size_t)S * D, DD = (size_t)D * D;

  const float* X  = (const float*)d_in[0];
  const float* Wq = (const float*)d_in[1];
  const float* Wk = (const float*)d_in[2];
  const float* Wv = (const float*)d_in[3];
  const float* Wo = (const float*)d_in[4];
  const float* bo = (const float*)d_in[5];
  const float* cs = (const float*)d_in[6];
  const float* sn = (const float*)d_in[7];

  u16* WB = (u16*)d_ws;
  u16* Xb = WB + DD;
  u16* Qb = Xb + SD;
  u16* Kb = Qb + SD;
  u16* Vb = Kb + SD;

  dim3 blk(256);
  dim3 g3(512);      // 8 XCD x 16 m x 4 n   (128x128 tiles)
  dim3 b3(256);

  cvt_f32_bf16<<<(int)(SD / 1024), blk, 0, stream>>>(X, Xb, (int)SD);
  cvt_f32_bf16<<<(int)(DD / 1024), blk, 0, stream>>>(Wq, WB, (int)DD);
  gemm_bt3<u16, false><<<g3, b3, 0, stream>>>(Xb, WB, Qb, nullptr, S, D, D);
  cvt_f32_bf16<<<(int)(DD / 1024), blk, 0, stream>>>(Wk, WB, (int)DD);
  gemm_bt3<u16, false><<<g3, b3, 0, stream>>>(Xb, WB, Kb, nullptr, S, D, D);
  cvt_f32_bf16<<<(int)(DD / 1024), blk, 0, stream>>>(Wv, WB, (int)DD);
  gemm_bt3<u16, false><<<g3, b3, 0, stream>>>(Xb, WB, Vb, nullptr, S, D, D);

  rope_qk<<<(S * H * 64) / 256, blk, 0, stream>>>(Qb, Kb, cs, sn);

  flash_attn<<<dim3(512), dim3(512), 0, stream>>>(Qb, Kb, Vb, Xb /*Ctx*/);

  cvt_f32_bf16<<<(int)(DD / 1024), blk, 0, stream>>>(Wo, WB, (int)DD);
  gemm_bt3<float, true><<<g3, b3, 0, stream>>>(Xb, WB, (float*)d_out, bo, S, D, D);
}

// Round 9
// 528.999 us; speedup vs baseline: 1.1693x; 1.0855x over previous
//
#include <hip/hip_runtime.h>

typedef unsigned short u16;
typedef __attribute__((ext_vector_type(8))) short s16x8;
typedef __attribute__((ext_vector_type(4))) float f32x4;

__device__ __forceinline__ u16 f2bf(float f) {
  unsigned u = __float_as_uint(f);
  u += 0x7fffu + ((u >> 16) & 1u);   // RNE
  return (u16)(u >> 16);
}
__device__ __forceinline__ float bf2f(u16 h) {
  return __uint_as_float(((unsigned)h) << 16);
}

typedef __attribute__((address_space(1))) const void gvoid_t;
typedef __attribute__((address_space(3))) void lvoid_t;
__device__ __forceinline__ void gload_lds16(const void* g, void* l) {
  __builtin_amdgcn_global_load_lds((gvoid_t*)g, (lvoid_t*)l, 16, 0, 0);
}

// ---------------- f32 -> bf16 convert (vectorized) ----------------
__global__ void cvt_f32_bf16(const float* __restrict__ in, u16* __restrict__ out, int n) {
  int i = (blockIdx.x * 256 + threadIdx.x) * 4;
  if (i >= n) return;
  float4 v = *(const float4*)(in + i);
  ushort4 o;
  o.x = f2bf(v.x); o.y = f2bf(v.y); o.z = f2bf(v.z); o.w = f2bf(v.w);
  *(ushort4*)(out + i) = o;
}

// ---------------- GEMM v4: C[M,N] = A[M,K]*B[N,K]^T ----------------
// 128x128 tile, BK=32, 256 thr (4 waves 2x2), triple-buffered 48KB LDS,
// counted vmcnt(4), one barrier per K-tile.
template<typename OutT, bool BIAS>
__global__ __launch_bounds__(256) void gemm_bt3(
    const u16* __restrict__ A, const u16* __restrict__ Bm,
    OutT* __restrict__ C, const float* __restrict__ bias,
    int M, int N, int K)
{
  __shared__ u16 As[3][128 * 32];
  __shared__ u16 Bs[3][128 * 32];

  const int t = threadIdx.x;
  const int lane = t & 63, wid = t >> 6;
  const int wm = wid >> 1, wn = wid & 1;
  const int lr = lane & 15, lk = lane >> 4;

  const int wg = blockIdx.x;
  const int xcd = wg & 7, j = wg >> 3;           // j 0..63
  const int m0 = (j & 15) * 128;
  const int n0 = ((xcd << 2) | (j >> 4)) * 128;

  const int nt = K >> 5;

  f32x4 acc[4][4] = {};

#define STAGE3(KT)                                                             \
  {                                                                            \
    const int bu_ = (KT) % 3;                                                  \
    const int k0_ = (KT) << 5;                                                 \
    _Pragma("unroll")                                                          \
    for (int it = 0; it < 2; ++it) {                                           \
      int id = it * 256 + t;                                                   \
      int r = id >> 2, c0 = id & 3;                                            \
      int cs = (c0 ^ ((r >> 1) & 3)) << 3;                                     \
      gload_lds16(A + (size_t)(m0 + r) * K + k0_ + cs, &As[bu_][id * 8]);      \
      gload_lds16(Bm + (size_t)(n0 + r) * K + k0_ + cs, &Bs[bu_][id * 8]);     \
    }                                                                          \
  }

  STAGE3(0);
  STAGE3(1);
  asm volatile("s_waitcnt vmcnt(4)" ::: "memory");
  __builtin_amdgcn_s_barrier();

  for (int kt = 0; kt < nt; ++kt) {
    const int bu = kt % 3;
    if (kt + 2 < nt) STAGE3(kt + 2);

    s16x8 af[4], bf[4];
#pragma unroll
    for (int i = 0; i < 4; ++i) {
      int ra = wm * 64 + i * 16 + lr;
      af[i] = *(const s16x8*)&As[bu][ra * 32 + ((lk ^ ((ra >> 1) & 3)) << 3)];
      int rb = wn * 64 + i * 16 + lr;
      bf[i] = *(const s16x8*)&Bs[bu][rb * 32 + ((lk ^ ((rb >> 1) & 3)) << 3)];
    }
    __builtin_amdgcn_s_setprio(1);
#pragma unroll
    for (int i = 0; i < 4; ++i)
#pragma unroll
      for (int jn = 0; jn < 4; ++jn)
        acc[i][jn] = __builtin_amdgcn_mfma_f32_16x16x32_bf16(af[i], bf[jn], acc[i][jn], 0, 0, 0);
    __builtin_amdgcn_s_setprio(0);

    asm volatile("s_waitcnt lgkmcnt(0)" ::: "memory");
    if (kt + 2 < nt)       { asm volatile("s_waitcnt vmcnt(4)" ::: "memory"); }
    else if (kt + 2 == nt) { asm volatile("s_waitcnt vmcnt(0)" ::: "memory"); }
    if (kt + 1 < nt) __builtin_amdgcn_s_barrier();
  }
#undef STAGE3

#pragma unroll
  for (int i = 0; i < 4; ++i) {
    int row_b = m0 + wm * 64 + i * 16 + lk * 4;
#pragma unroll
    for (int jn = 0; jn < 4; ++jn) {
      int col = n0 + wn * 64 + jn * 16 + lr;
      float bv = BIAS ? bias[col] : 0.f;
#pragma unroll
      for (int r = 0; r < 4; ++r) {
        float v = acc[i][jn][r] + bv;
        size_t off = (size_t)(row_b + r) * N + col;
        if constexpr (sizeof(OutT) == 2) ((u16*)C)[off] = f2bf(v);
        else                             ((float*)C)[off] = v;
      }
    }
  }
}

// ---------------- Fused QKV GEMM: Bstk = [Wq;Wk;Wv] (12288 x 4096 bf16) ----------------
// Same body as gemm_bt3; grid 1536 = 8 XCD x (16 m x 12 n-panels); 3 blocks/CU.
__global__ __launch_bounds__(256) void gemm_qkv(
    const u16* __restrict__ A, const u16* __restrict__ Bstk,
    u16* __restrict__ Qb, u16* __restrict__ Kb, u16* __restrict__ Vb,
    int M, int K)
{
  __shared__ u16 As[3][128 * 32];
  __shared__ u16 Bs[3][128 * 32];

  const int t = threadIdx.x;
  const int lane = t & 63, wid = t >> 6;
  const int wm = wid >> 1, wn = wid & 1;
  const int lr = lane & 15, lk = lane >> 4;

  const int wg = blockIdx.x;
  const int xcd = wg & 7, j = wg >> 3;            // j 0..191
  const int m0 = (j & 15) * 128;
  const int n0 = (xcd * 12 + (j >> 4)) * 128;     // 0..12160

  const int nt = K >> 5;

  f32x4 acc[4][4] = {};

#define STAGEQ(KT)                                                             \
  {                                                                            \
    const int bu_ = (KT) % 3;                                                  \
    const int k0_ = (KT) << 5;                                                 \
    _Pragma("unroll")                                                          \
    for (int it = 0; it < 2; ++it) {                                           \
      int id = it * 256 + t;                                                   \
      int r = id >> 2, c0 = id & 3;                                            \
      int cs = (c0 ^ ((r >> 1) & 3)) << 3;                                     \
      gload_lds16(A + (size_t)(m0 + r) * K + k0_ + cs, &As[bu_][id * 8]);      \
      gload_lds16(Bstk + (size_t)(n0 + r) * K + k0_ + cs, &Bs[bu_][id * 8]);   \
    }                                                                          \
  }

  STAGEQ(0);
  STAGEQ(1);
  asm volatile("s_waitcnt vmcnt(4)" ::: "memory");
  __builtin_amdgcn_s_barrier();

  for (int kt = 0; kt < nt; ++kt) {
    const int bu = kt % 3;
    if (kt + 2 < nt) STAGEQ(kt + 2);

    s16x8 af[4], bf[4];
#pragma unroll
    for (int i = 0; i < 4; ++i) {
      int ra = wm * 64 + i * 16 + lr;
      af[i] = *(const s16x8*)&As[bu][ra * 32 + ((lk ^ ((ra >> 1) & 3)) << 3)];
      int rb = wn * 64 + i * 16 + lr;
      bf[i] = *(const s16x8*)&Bs[bu][rb * 32 + ((lk ^ ((rb >> 1) & 3)) << 3)];
    }
    __builtin_amdgcn_s_setprio(1);
#pragma unroll
    for (int i = 0; i < 4; ++i)
#pragma unroll
      for (int jn = 0; jn < 4; ++jn)
        acc[i][jn] = __builtin_amdgcn_mfma_f32_16x16x32_bf16(af[i], bf[jn], acc[i][jn], 0, 0, 0);
    __builtin_amdgcn_s_setprio(0);

    asm volatile("s_waitcnt lgkmcnt(0)" ::: "memory");
    if (kt + 2 < nt)       { asm volatile("s_waitcnt vmcnt(4)" ::: "memory"); }
    else if (kt + 2 == nt) { asm volatile("s_waitcnt vmcnt(0)" ::: "memory"); }
    if (kt + 1 < nt) __builtin_amdgcn_s_barrier();
  }
#undef STAGEQ

  // route output block to Q/K/V by n0 (BN=128 divides the 4096 boundaries)
  u16* Cp; int nb;
  if (n0 < 4096)      { Cp = Qb; nb = n0; }
  else if (n0 < 8192) { Cp = Kb; nb = n0 - 4096; }
  else                { Cp = Vb; nb = n0 - 8192; }

#pragma unroll
  for (int i = 0; i < 4; ++i) {
    int row_b = m0 + wm * 64 + i * 16 + lk * 4;
#pragma unroll
    for (int jn = 0; jn < 4; ++jn) {
      int col = nb + wn * 64 + jn * 16 + lr;
#pragma unroll
      for (int r = 0; r < 4; ++r)
        Cp[(size_t)(row_b + r) * 4096 + col] = f2bf(acc[i][jn][r]);
    }
  }
}

// ---------------- RoPE on Q and K in place (bf16) ----------------
__global__ void rope_qk(u16* __restrict__ Q, u16* __restrict__ Kt,
                        const float* __restrict__ cosp, const float* __restrict__ sinp) {
  int i = blockIdx.x * 256 + threadIdx.x;   // over S*H*64
  int d = i & 63;
  int h = (i >> 6) & 31;
  int s = i >> 11;
  float c = cosp[s * 128 + d], sn = sinp[s * 128 + d];
  size_t base = (size_t)s * 4096 + h * 128 + d;
  float q1 = bf2f(Q[base]), q2 = bf2f(Q[base + 64]);
  Q[base]      = f2bf(q1 * c - q2 * sn);
  Q[base + 64] = f2bf(q2 * c + q1 * sn);
  float k1 = bf2f(Kt[base]), k2 = bf2f(Kt[base + 64]);
  Kt[base]      = f2bf(k1 * c - k2 * sn);
  Kt[base + 64] = f2bf(k2 * c + k1 * sn);
}

// ---------------- Flash attention (causal): QBLK=128, KVBLK=64, 8 waves ----------------
// 64KB LDS -> 2 blocks/CU; complementary pairing (long+short) -> 36 tiles/CU.
__global__ __launch_bounds__(512) void flash_attn(
    const u16* __restrict__ Q, const u16* __restrict__ Kg, const u16* __restrict__ Vg,
    u16* __restrict__ Ctx)
{
  const int D = 4096;
  __shared__ u16 Ks[2][64 * 128];  // [kv][d-chunk], chunk XOR-swizzled by (kv&7)
  __shared__ u16 Vt[128 * 64];     // [d][kv], kv XOR-swizzled by (((d>>3)^d)&7)<<3
  __shared__ u16 Ps[8][16 * 64];   // per-wave P, col XOR-swizzled by ((q>>1)&7)<<3

  const int t = threadIdx.x, lane = t & 63, wid = t >> 6;
  const int lr = lane & 15, lk = lane >> 4;

  const int wg = blockIdx.x;              // 0..511
  const int xcd = wg & 7, j = wg >> 3;    // j 0..63 local
  // complementary pairing: wg c (j<32, long, bx 15..8) co-resides with
  // wg c+256 (j>=32, short, bx 0..7); pair sum = 36 tiles uniformly.
  const int bx = (j < 32) ? (15 - (j >> 2)) : ((j - 32) >> 2);
  const int h = xcd * 4 + (j & 3);        // 4 heads per XCD
  const int q0 = bx * 128;
  const int qw0 = q0 + wid * 16;

  s16x8 qf[4];
#pragma unroll
  for (int kc = 0; kc < 4; ++kc)
    qf[kc] = *(const s16x8*)(Q + (size_t)(qw0 + lr) * D + h * 128 + kc * 32 + lk * 8);

  f32x4 o[8] = {};
  float m_r[4] = {-1e30f, -1e30f, -1e30f, -1e30f};
  float l_r[4] = {0.f, 0.f, 0.f, 0.f};

  const int ntiles = 2 * bx + 2;
  const float scale2 = 0.12751779f;       // (1/sqrt(128)) * log2(e)

  const int ch = t & 15, kv2 = (t >> 4) * 2;

  // prologue: K(0) gloads; V(0) regs -> Vt
  {
    const u16* src = Vg + (size_t)kv2 * D + h * 128 + ch * 8;
    s16x8 a0 = *(const s16x8*)src;
    s16x8 a1 = *(const s16x8*)(src + D);
#pragma unroll
    for (int it = 0; it < 2; ++it) {
      int id = it * 512 + t;
      int kv = id >> 4, c0 = id & 15;
      gload_lds16(Kg + (size_t)kv * D + h * 128 + ((c0 ^ (kv & 7)) << 3), &Ks[0][id * 8]);
    }
#pragma unroll
    for (int jj = 0; jj < 8; ++jj) {
      int d = ch * 8 + jj;
      int sw = ((ch ^ jj) & 7) << 3;
      unsigned pr = (unsigned)(u16)a0[jj] | ((unsigned)(u16)a1[jj] << 16);
      *(unsigned*)&Vt[d * 64 + (kv2 ^ sw)] = pr;
    }
  }

  for (int kt = 0; kt < ntiles; ++kt) {
    const int b = kt & 1;
    const int kv0 = kt * 64;
    __syncthreads();   // K(kt) landed (vmcnt drain), Vt(kt) visible

    s16x8 a0, a1;
    const bool pf = (kt + 1 < ntiles);
    if (pf) {
      const u16* src = Vg + (size_t)(kv0 + 64 + kv2) * D + h * 128 + ch * 8;
      a0 = *(const s16x8*)src;
      a1 = *(const s16x8*)(src + D);
#pragma unroll
      for (int it = 0; it < 2; ++it) {
        int id = it * 512 + t;
        int kv = id >> 4, c0 = id & 15;
        gload_lds16(Kg + (size_t)(kv0 + 64 + kv) * D + h * 128 + ((c0 ^ (kv & 7)) << 3),
                    &Ks[b ^ 1][id * 8]);
      }
    }

    if (kv0 <= qw0 + 15) {
      const bool masked = (kv0 + 63 > qw0);

      f32x4 st[4] = {};
      __builtin_amdgcn_s_setprio(1);
#pragma unroll
      for (int nt = 0; nt < 4; ++nt) {
        int kv = nt * 16 + lr;
        int sw = kv & 7;
#pragma unroll
        for (int kc = 0; kc < 4; ++kc) {
          s16x8 kf = *(const s16x8*)&Ks[b][kv * 128 + (((4 * kc + lk) ^ sw) << 3)];
          st[nt] = __builtin_amdgcn_mfma_f32_16x16x32_bf16(qf[kc], kf, st[nt], 0, 0, 0);
        }
      }
      __builtin_amdgcn_s_setprio(0);

      float pmax_[4];
#pragma unroll
      for (int r = 0; r < 4; ++r) {
        int q_r = qw0 + lk * 4 + r;
        if (masked) {
#pragma unroll
          for (int nt = 0; nt < 4; ++nt) {
            float sv = st[nt][r] * scale2;
            if (kv0 + nt * 16 + lr > q_r) sv = -1e30f;
            st[nt][r] = sv;
          }
        } else {
#pragma unroll
          for (int nt = 0; nt < 4; ++nt) st[nt][r] *= scale2;
        }
        float pm = fmaxf(fmaxf(st[0][r], st[1][r]), fmaxf(st[2][r], st[3][r]));
        pm = fmaxf(pm, __shfl_xor(pm, 1));
        pm = fmaxf(pm, __shfl_xor(pm, 2));
        pm = fmaxf(pm, __shfl_xor(pm, 4));
        pm = fmaxf(pm, __shfl_xor(pm, 8));
        pmax_[r] = pm;
      }
      bool nr = (pmax_[0] > m_r[0] + 8.f) || (pmax_[1] > m_r[1] + 8.f) ||
                (pmax_[2] > m_r[2] + 8.f) || (pmax_[3] > m_r[3] + 8.f);
      if (__any(nr)) {
#pragma unroll
        for (int r = 0; r < 4; ++r) {
          float mn = fmaxf(m_r[r], pmax_[r]);
          float al = __builtin_amdgcn_exp2f(m_r[r] - mn);
          m_r[r] = mn; l_r[r] *= al;
#pragma unroll
          for (int nb = 0; nb < 8; ++nb) o[nb][r] *= al;
        }
      }
#pragma unroll
      for (int r = 0; r < 4; ++r) {
        int ql = lk * 4 + r;
        int swp = ((ql >> 1) & 7) << 3;
        float ps = 0.f;
#pragma unroll
        for (int nt = 0; nt < 4; ++nt) {
          float pv = __builtin_amdgcn_exp2f(st[nt][r] - m_r[r]);
          ps += pv;
          Ps[wid][ql * 64 + ((nt * 16 + lr) ^ swp)] = f2bf(pv);
        }
        ps += __shfl_xor(ps, 1);
        ps += __shfl_xor(ps, 2);
        ps += __shfl_xor(ps, 4);
        ps += __shfl_xor(ps, 8);
        l_r[r] += ps;
      }
      asm volatile("s_waitcnt lgkmcnt(0)" ::: "memory");

      s16x8 pa[2];
#pragma unroll
      for (int ks = 0; ks < 2; ++ks) {
        int col = (ks * 32 + lk * 8) ^ (((lr >> 1) & 7) << 3);
        pa[ks] = *(const s16x8*)&Ps[wid][lr * 64 + col];
      }

      __builtin_amdgcn_s_setprio(1);
#pragma unroll
      for (int ks = 0; ks < 2; ++ks) {
#pragma unroll
        for (int nb = 0; nb < 8; ++nb) {
          int d = nb * 16 + lr;
          int g = (((d >> 3) ^ d) & 7) << 3;
          s16x8 vf = *(const s16x8*)&Vt[d * 64 + ((ks * 32 + lk * 8) ^ g)];
          o[nb] = __builtin_amdgcn_mfma_f32_16x16x32_bf16(pa[ks], vf, o[nb], 0, 0, 0);
        }
      }
      __builtin_amdgcn_s_setprio(0);
    }

    if (pf) {
      __builtin_amdgcn_s_barrier();   // exec-only: K-prefetch stays in flight
#pragma unroll
      for (int jj = 0; jj < 8; ++jj) {
        int d = ch * 8 + jj;
        int sw = ((ch ^ jj) & 7) << 3;
        unsigned pr = (unsigned)(u16)a0[jj] | ((unsigned)(u16)a1[jj] << 16);
        *(unsigned*)&Vt[d * 64 + (kv2 ^ sw)] = pr;
      }
    }
  }

#pragma unroll
  for (int r = 0; r < 4; ++r) {
    float inv = 1.f / l_r[r];
    int q_r = qw0 + lk * 4 + r;
#pragma unroll
    for (int nb = 0; nb < 8; ++nb)
      Ctx[(size_t)q_r * D + h * 128 + nb * 16 + lr] = f2bf(o[nb][r] * inv);
  }
}

// ---------------- launcher ----------------
extern "C" void kernel_launch(void* const* d_in, const int* in_sizes, int n_in,
                              void* d_out, int out_size, void* d_ws, size_t ws_size,
                              hipStream_t stream) {
  const int S = 2048, D = 4096, H = 32;
  const size_t SD = (size_t)S * D, DD = (size_t)D * D;

  const float* X  = (const float*)d_in[0];
  const float* Wq = (const float*)d_in[1];
  const float* Wk = (const float*)d_in[2];
  const float* Wv = (const float*)d_in[3];
  const float* Wo = (const float*)d_in[4];
  const float* bo = (const float*)d_in[5];
  const float* cs = (const float*)d_in[6];
  const float* sn = (const float*)d_in[7];

  dim3 blk(256);
  dim3 g3(512);      // 8 XCD x 16 m x 4 n   (128x128 tiles)
  dim3 b3(256);

  const size_t need_fused = (3 * DD + 4 * SD) * sizeof(u16);   // 160 MiB

  if (ws_size >= need_fused) {
    // fused-QKV path: WB3 = [Wq;Wk;Wv] bf16 stacked
    u16* WB3 = (u16*)d_ws;
    u16* Xb  = WB3 + 3 * DD;
    u16* Qb  = Xb + SD;
    u16* Kb  = Qb + SD;
    u16* Vb  = Kb + SD;

    cvt_f32_bf16<<<(int)(SD / 1024), blk, 0, stream>>>(X, Xb, (int)SD);
    cvt_f32_bf16<<<(int)(DD / 1024), blk, 0, stream>>>(Wq, WB3, (int)DD);
    cvt_f32_bf16<<<(int)(DD / 1024), blk, 0, stream>>>(Wk, WB3 + DD, (int)DD);
    cvt_f32_bf16<<<(int)(DD / 1024), blk, 0, stream>>>(Wv, WB3 + 2 * DD, (int)DD);

    gemm_qkv<<<dim3(1536), b3, 0, stream>>>(Xb, WB3, Qb, Kb, Vb, S, D);

    rope_qk<<<(S * H * 64) / 256, blk, 0, stream>>>(Qb, Kb, cs, sn);
    flash_attn<<<dim3(512), dim3(512), 0, stream>>>(Qb, Kb, Vb, Xb /*Ctx*/);

    cvt_f32_bf16<<<(int)(DD / 1024), blk, 0, stream>>>(Wo, WB3, (int)DD);
    gemm_bt3<float, true><<<g3, b3, 0, stream>>>(Xb, WB3, (float*)d_out, bo, S, D, D);
  } else {
    // fallback: serial per-weight path (96 MiB)
    u16* WB = (u16*)d_ws;
    u16* Xb = WB + DD;
    u16* Qb = Xb + SD;
    u16* Kb = Qb + SD;
    u16* Vb = Kb + SD;

    cvt_f32_bf16<<<(int)(SD / 1024), blk, 0, stream>>>(X, Xb, (int)SD);
    cvt_f32_bf16<<<(int)(DD / 1024), blk, 0, stream>>>(Wq, WB, (int)DD);
    gemm_bt3<u16, false><<<g3, b3, 0, stream>>>(Xb, WB, Qb, nullptr, S, D, D);
    cvt_f32_bf16<<<(int)(DD / 1024), blk, 0, stream>>>(Wk, WB, (int)DD);
    gemm_bt3<u16, false><<<g3, b3, 0, stream>>>(Xb, WB, Kb, nullptr, S, D, D);
    cvt_f32_bf16<<<(int)(DD / 1024), blk, 0, stream>>>(Wv, WB, (int)DD);
    gemm_bt3<u16, false><<<g3, b3, 0, stream>>>(Xb, WB, Vb, nullptr, S, D, D);

    rope_qk<<<(S * H * 64) / 256, blk, 0, stream>>>(Qb, Kb, cs, sn);
    flash_attn<<<dim3(512), dim3(512), 0, stream>>>(Qb, Kb, Vb, Xb /*Ctx*/);

    cvt_f32_bf16<<<(int)(DD / 1024), blk, 0, stream>>>(Wo, WB, (int)DD);
    gemm_bt3<float, true><<<g3, b3, 0, stream>>>(Xb, WB, (float*)d_out, bo, S, D, D);
  }
}